// Round 12
// baseline (1294.614 us; speedup 1.0000x reference)
//
#include <hip/hip_runtime.h>
#include <math.h>

#define DD 256
#define KK 512
#define TM 128
#define TKC 128
#define NCHUNK 4
#define DSL 32
#define NSL 8
#define NSLICES 32
#define SPLIT 8

typedef float float4v __attribute__((ext_vector_type(4)));
typedef float float2v __attribute__((ext_vector_type(2)));

__device__ __forceinline__ void gld_lds16(const void* g, void* l) {
    __builtin_amdgcn_global_load_lds((const __attribute__((address_space(1))) void*)g,
                                     (__attribute__((address_space(3))) void*)l, 16, 0, 0);
}

// ---------------------------------------------------------------------------
// argmin over K=512 centroids for a 128-point block, 8x8 per-thread tile.
// Round-12: R11 verbatim EXCEPT launch_bounds(256,2) -> (256,1).
// R11 post-mortem: allocator self-capped at 128 VGPR (its occupancy
// heuristic) and spilled accB -> WRITE 32MB, perf neutral.  The kernel needs
// ~230 VGPR; at (256,1) the allocator may take them.  Residency is capped
// at 2 blocks/CU by the 64KB LDS either way, and VGPR<=256 sustains the
// same 2 waves/SIMD — so no occupancy loss unless VGPR>256.
// SPILL GATE: WRITE ~0.5MB + VGPR 180-256 = success; WRITE 32MB or
// VGPR>256 = revert to R10 permanently.
// ---------------------------------------------------------------------------
template<bool FIRST>
__global__ __launch_bounds__(256, 1)
void argmin_kernel(const float* __restrict__ x, const float* __restrict__ cent,
                   const float* __restrict__ cc,
                   const int N,
                   int* __restrict__ assign_out,
                   const int* __restrict__ prev, const int pstride,
                   unsigned int* __restrict__ mismatch,
                   int* __restrict__ counts)
{
    __shared__ float xs[2][TM * DSL];   // 2 x 16 KB
    __shared__ float cs[2][TKC * DSL];  // 2 x 16 KB

    const int tid  = threadIdx.x;
    const int w    = tid >> 6;
    const int lane = tid & 63;
    const int tr   = tid >> 4;   // 0..15 (point dim)
    const int tc   = tid & 15;   // 0..15 (centroid dim)
    const long long rowbase = (long long)blockIdx.x * TM;

    float minv[8]; int mini[8];
#pragma unroll
    for (int i = 0; i < 8; ++i) { minv[i] = __builtin_inff(); mini[i] = 0; }

    const int r_st  = (w << 3) + (lane >> 3);
    const int slot4 = (lane & 7) << 2;

    // R1's exact STAGE: 8 global_load_lds per thread (4 x + 4 cent)
#define STAGE(BUF, S) do {                                                        \
        const int d0_    = ((S) & 7) * DSL;                                       \
        const int cbase_ = ((S) >> 3) * TKC;                                      \
        _Pragma("unroll")                                                         \
        for (int call = 0; call < 4; ++call) {                                    \
            int r  = (call << 5) + r_st;                                          \
            int dl = slot4 ^ (((r >> 2) & 7) << 2);                               \
            long long p = rowbase + r; if (p > N - 1) p = N - 1;                  \
            gld_lds16(x + p * DD + d0_ + dl, &xs[(BUF)][((call << 2) + w) << 8]); \
            gld_lds16(cent + (long long)(cbase_ + r) * DD + d0_ + dl,             \
                      &cs[(BUF)][((call << 2) + w) << 8]);                        \
        }                                                                         \
    } while (0)

    STAGE(0, 0);
    int s = 0;
    float2v accA[4][8];   // rows tr*4 + i
    float2v accB[4][8];   // rows 64 + tr*4 + i

#pragma unroll 1
    for (int chunk = 0; chunk < NCHUNK; ++chunk) {
        float cchalf[8];
#pragma unroll
        for (int j = 0; j < 8; ++j) {
            int r = ((j >> 2) << 6) + (tc << 2) + (j & 3);
            cchalf[j] = 0.5f * cc[chunk * TKC + r];   // exact scale
        }
#pragma unroll
        for (int i = 0; i < 4; ++i)
#pragma unroll
            for (int j = 0; j < 8; ++j) {
                accA[i][j] = (float2v){0.0f, 0.0f};
                accB[i][j] = (float2v){0.0f, 0.0f};
            }

#pragma unroll 1
        for (int sl = 0; sl < NSL; ++sl) {
            const int buf = s & 1;
            __syncthreads();                      // compiler drains vmcnt here
            if (s + 1 < NSLICES) STAGE(buf ^ 1, s + 1);
#pragma unroll
            for (int g = 0; g < 8; ++g) {
                const int dl = g << 2;
                float4v bc[8];
#pragma unroll
                for (int j = 0; j < 8; ++j) {
                    int r = ((j >> 2) << 6) + (tc << 2) + (j & 3);
                    bc[j] = *(const float4v*)&cs[buf][(r << 5) + (dl ^ (((r >> 2) & 7) << 2))];
                }
                // half A: rows tr*4+i (R10's exact row mapping)
#pragma unroll
                for (int i = 0; i < 4; ++i) {
                    int r = (tr << 2) + i;
                    const float4v ax =
                        *(const float4v*)&xs[buf][(r << 5) + (dl ^ (((r >> 2) & 7) << 2))];
                    const float2v axl = __builtin_shufflevector(ax, ax, 0, 1);
                    const float2v axh = __builtin_shufflevector(ax, ax, 2, 3);
#pragma unroll
                    for (int j = 0; j < 8; ++j) {
                        const float2v bcl = __builtin_shufflevector(bc[j], bc[j], 0, 1);
                        const float2v bch = __builtin_shufflevector(bc[j], bc[j], 2, 3);
                        float2v t = accA[i][j];
                        t = __builtin_elementwise_fma(axl, bcl, t);   // v_pk_fma_f32
                        t = __builtin_elementwise_fma(axh, bch, t);   // v_pk_fma_f32
                        accA[i][j] = t;
                    }
                }
                // half B: rows 64+tr*4+i (R1's upper-half row mapping)
#pragma unroll
                for (int i = 0; i < 4; ++i) {
                    int r = 64 + (tr << 2) + i;
                    const float4v ax =
                        *(const float4v*)&xs[buf][(r << 5) + (dl ^ (((r >> 2) & 7) << 2))];
                    const float2v axl = __builtin_shufflevector(ax, ax, 0, 1);
                    const float2v axh = __builtin_shufflevector(ax, ax, 2, 3);
#pragma unroll
                    for (int j = 0; j < 8; ++j) {
                        const float2v bcl = __builtin_shufflevector(bc[j], bc[j], 0, 1);
                        const float2v bch = __builtin_shufflevector(bc[j], bc[j], 2, 3);
                        float2v t = accB[i][j];
                        t = __builtin_elementwise_fma(axl, bcl, t);   // v_pk_fma_f32
                        t = __builtin_elementwise_fma(axh, bch, t);   // v_pk_fma_f32
                        accB[i][j] = t;
                    }
                }
            }
            ++s;
        }
        // fold this chunk into running min (registers only):
        // score = 0.5*cc - dot  (same argmin as the true distance — R10-verified)
        {
#pragma clang fp contract(off)
#pragma unroll
            for (int i = 0; i < 4; ++i)
#pragma unroll
                for (int j = 0; j < 8; ++j) {
                    int r = ((j >> 2) << 6) + (tc << 2) + (j & 3);
                    const int cidx = chunk * TKC + r;
                    float dotA   = accA[i][j][0] + accA[i][j][1];
                    float scoreA = cchalf[j] - dotA;
                    if (scoreA < minv[i])     { minv[i]     = scoreA; mini[i]     = cidx; }
                    float dotB   = accB[i][j][0] + accB[i][j][1];
                    float scoreB = cchalf[j] - dotB;
                    if (scoreB < minv[4 + i]) { minv[4 + i] = scoreB; mini[4 + i] = cidx; }
                }
        }
    }
#undef STAGE

    // reduce across the 16 tc lanes (bits 0..3 of lane), first-min tie-break
#pragma unroll
    for (int i = 0; i < 8; ++i) {
#pragma unroll
        for (int off = 1; off < 16; off <<= 1) {
            float ov = __shfl_xor(minv[i], off);
            int   oi = __shfl_xor(mini[i], off);
            if (ov < minv[i] || (ov == minv[i] && oi < mini[i])) { minv[i] = ov; mini[i] = oi; }
        }
    }
    if (tc == 0) {
        unsigned int mis = 0;
#pragma unroll
        for (int i = 0; i < 8; ++i) {
            // i<4 -> row tr*4+i (half A); i>=4 -> row 64+tr*4+(i&3) (half B)
            long long p = rowbase + ((i >> 2) << 6) + (tr << 2) + (i & 3);
            if (p < N) {
                assign_out[p] = mini[i];
                if (FIRST) {
                    atomicAdd(&counts[mini[i]], 1);      // fused hist
                }
                if (prev != nullptr && prev[p * pstride] != mini[i]) ++mis;
            }
        }
        if (mis) atomicAdd(mismatch, mis);
    }
}

// row-wise squared norms (one wave per row, 256 cols) — used for centroids only
__global__ void sqnorm_kernel(const float* __restrict__ m, float* __restrict__ out, const int n)
{
    const int w = threadIdx.x >> 6, lane = threadIdx.x & 63;
    const int row = (blockIdx.x << 2) + w;
    if (row >= n) return;
    const float4v v = *(const float4v*)&m[(long long)row * DD + (lane << 2)];
    float s = v[0]*v[0] + v[1]*v[1] + v[2]*v[2] + v[3]*v[3];
#pragma unroll
    for (int off = 1; off < 64; off <<= 1) s += __shfl_xor(s, off);
    if (lane == 0) out[row] = s;
}

// ---------------------------------------------------------------------------
// Segment-sum via counting sort + gather.
// Q40 fixed-point accumulation is order-independent => deterministic.
// (hist is fused into argmin pass 1's epilogue.)
// ---------------------------------------------------------------------------
__global__ __launch_bounds__(KK)
void scan_kernel(const int* __restrict__ counts, int* __restrict__ starts, int* __restrict__ cursor)
{
    __shared__ int buf[2][KK];
    const int t = threadIdx.x;
    const int v = counts[t];
    buf[0][t] = v;
    __syncthreads();
    int src = 0;
#pragma unroll
    for (int off = 1; off < KK; off <<= 1) {
        int val = buf[src][t];
        if (t >= off) val += buf[src][t - off];
        buf[src ^ 1][t] = val;
        src ^= 1;
        __syncthreads();
    }
    const int excl = buf[src][t] - v;
    starts[t] = excl;
    cursor[t] = excl;
}

__global__ void scatter_kernel(const int* __restrict__ assign, int* __restrict__ cursor,
                               int* __restrict__ idx, const int N)
{
    const int p = blockIdx.x * 256 + threadIdx.x;
    if (p >= N) return;
    const int a = assign[p];
    const int pos = atomicAdd(&cursor[a], 1);
    idx[pos] = p;
}

__global__ __launch_bounds__(256)
void gather_kernel(const float* __restrict__ x, const int* __restrict__ idx,
                   const int* __restrict__ starts, const int* __restrict__ counts,
                   unsigned long long* __restrict__ sums)
{
    const int c    = blockIdx.x / SPLIT;
    const int part = blockIdx.x % SPLIT;
    const int d    = threadIdx.x;
    const int start = starts[c], cnt = counts[c];
    const int chunk = (cnt + SPLIT - 1) / SPLIT;
    const int i0 = part * chunk;
    int i1 = i0 + chunk; if (i1 > cnt) i1 = cnt;
    if (i1 <= i0) return;

    long long acc = 0;
    int i = i0;
    for (; i + 4 <= i1; i += 4) {
        const int p0 = idx[start + i + 0];
        const int p1 = idx[start + i + 1];
        const int p2 = idx[start + i + 2];
        const int p3 = idx[start + i + 3];
        const float v0 = x[(long long)p0 * DD + d];
        const float v1 = x[(long long)p1 * DD + d];
        const float v2 = x[(long long)p2 * DD + d];
        const float v3 = x[(long long)p3 * DD + d];
        acc += __double2ll_rn((double)v0 * 1099511627776.0);   // 2^40
        acc += __double2ll_rn((double)v1 * 1099511627776.0);
        acc += __double2ll_rn((double)v2 * 1099511627776.0);
        acc += __double2ll_rn((double)v3 * 1099511627776.0);
    }
    for (; i < i1; ++i) {
        const int p = idx[start + i];
        acc += __double2ll_rn((double)x[(long long)p * DD + d] * 1099511627776.0);
    }
    atomicAdd(&sums[(size_t)c * DD + d], (unsigned long long)acc);
}

// EMA update + squared norms of updated centroids
__global__ void update_kernel(const float* __restrict__ cent,
                              const unsigned long long* __restrict__ sums,
                              const int* __restrict__ counts,
                              float* __restrict__ updated, float* __restrict__ cc2)
{
    const int c = blockIdx.x, d = threadIdx.x;
    const int w = d >> 6, lane = d & 63;
    __shared__ float red[4];
    float u;
    {
#pragma clang fp contract(off)
        const float cnt = (float)counts[c];
        const float sf  = (float)((double)(long long)sums[(size_t)c * DD + d] * (1.0 / 1099511627776.0));
        const float nc  = sf / cnt;
        u = 0.01f * cent[(size_t)c * DD + d] + 0.99f * nc;
    }
    updated[(size_t)c * DD + d] = u;
    float s = u * u;
#pragma unroll
    for (int off = 1; off < 64; off <<= 1) s += __shfl_xor(s, off);
    if (lane == 0) red[w] = s;
    __syncthreads();
    if (d == 0) cc2[c] = (red[0] + red[1]) + (red[2] + red[3]);
}

// final select per match flag; everything emitted as f32
__global__ void output_kernel(const unsigned int* __restrict__ mismatch,
                              const int* __restrict__ a1, const int* __restrict__ a2,
                              const float* __restrict__ cent, const float* __restrict__ updated,
                              float* __restrict__ out, const int N, const int total)
{
    const int g = blockIdx.x * 256 + threadIdx.x;
    if (g >= total) return;
    const bool match = (*mismatch == 0u);
    if (g < N)       out[g] = (float)(match ? a2[g] : a1[g]);
    else if (g == N) out[g] = match ? 1.0f : 0.0f;
    else {
        const int e = g - N - 1;
        out[g] = match ? updated[e] : cent[e];
    }
}

extern "C" void kernel_launch(void* const* d_in, const int* in_sizes, int n_in,
                              void* d_out, int out_size, void* d_ws, size_t ws_size,
                              hipStream_t stream)
{
    const float* x    = (const float*)d_in[0];
    const float* cent = (const float*)d_in[1];
    const int*   prev = (const int*)d_in[2];
    const int N = in_sizes[0] / DD;
    const int pstride = (n_in >= 3 && in_sizes[2] >= 2 * N) ? 2 : 1;  // int64 defensive

    char* ws = (char*)d_ws;
    size_t off = 0;
    auto alloc = [&](size_t b) { void* p = ws + off; off += (b + 255) & ~(size_t)255; return p; };
    int*   assign1 = (int*)alloc((size_t)N * 4);
    int*   assign2 = (int*)alloc((size_t)N * 4);
    float* cc      = (float*)alloc(KK * 4);
    float* cc2v    = (float*)alloc(KK * 4);
    int*   counts  = (int*)alloc(KK * 4);
    int*   starts  = (int*)alloc(KK * 4);
    int*   cursor  = (int*)alloc(KK * 4);
    int*   idx     = (int*)alloc((size_t)N * 4);
    unsigned long long* sums = (unsigned long long*)alloc((size_t)KK * DD * 8);
    float* updated = (float*)alloc((size_t)KK * DD * 4);
    unsigned int* mismatch = (unsigned int*)alloc(256);

    hipMemsetAsync(counts, 0, KK * 4, stream);
    hipMemsetAsync(sums, 0, (size_t)KK * DD * 8, stream);
    hipMemsetAsync(mismatch, 0, 4, stream);

    sqnorm_kernel<<<(KK + 3) / 4, 256, 0, stream>>>(cent, cc, KK);

    const int gb = (N + TM - 1) / TM;
    argmin_kernel<true><<<gb, 256, 0, stream>>>(x, cent, cc, N, assign1,
                                                prev, pstride, mismatch, counts);

    // counting-sort + gather segment sum (hist fused into argmin pass 1)
    scan_kernel<<<1, KK, 0, stream>>>(counts, starts, cursor);
    scatter_kernel<<<(N + 255) / 256, 256, 0, stream>>>(assign1, cursor, idx, N);
    gather_kernel<<<KK * SPLIT, 256, 0, stream>>>(x, idx, starts, counts, sums);

    update_kernel<<<KK, 256, 0, stream>>>(cent, sums, counts, updated, cc2v);

    argmin_kernel<false><<<gb, 256, 0, stream>>>(x, updated, cc2v, N, assign2,
                                                 nullptr, 1, nullptr, nullptr);

    output_kernel<<<(out_size + 255) / 256, 256, 0, stream>>>(mismatch, assign1, assign2,
                                                              cent, updated, (float*)d_out,
                                                              N, out_size);
}

// Round 13
// 1102.916 us; speedup vs baseline: 1.1738x; 1.1738x over previous
//
#include <hip/hip_runtime.h>
#include <math.h>

#define DD 256
#define KK 512
#define TM 64
#define TKC 64
#define NCHUNK 8
#define DSL 32
#define NSL 8
#define NSLICES 64
#define SPLIT 8

typedef float float4v __attribute__((ext_vector_type(4)));
typedef float float2v __attribute__((ext_vector_type(2)));

__device__ __forceinline__ void gld_lds16(const void* g, void* l) {
    __builtin_amdgcn_global_load_lds((const __attribute__((address_space(1))) void*)g,
                                     (__attribute__((address_space(3))) void*)l, 16, 0, 0);
}

// ---------------------------------------------------------------------------
// argmin over K=512 centroids for a 64-point block.
// Round-13: occupancy push along the PROVEN axis.  R1-vs-R10 evidence: this
// loop is latency-bound (R1 had half the LDS instrs at 2 blk/CU and was 47%
// slower than R10 at 3 blk/CU).  8x8 tile condemned (R11 spills at 128 regs,
// R12 overflows the unified file at full alloc).  So: TKC 128->64 (R6-class
// edit): LDS 48->32KB -> 5 blocks/CU, acc2[4][4]=32 regs (pressure drops),
// chunks 8.  LDS instr count +33% is absorbed (~35% pipe util); 5 waves/SIMD
// lift VALUBusy 50 -> ~70%.  STAGE: xs and cs each 2 calls, same dest
// formula and swizzle algebra as R10 (verified line-by-line).
// NO-SPILL GATE: LDS 32768, VGPR<=128, WRITE ~3.4MB, FETCH ~165MB; else R10.
// ---------------------------------------------------------------------------
template<bool FIRST>
__global__ __launch_bounds__(256, 2)
void argmin_kernel(const float* __restrict__ x, const float* __restrict__ cent,
                   const float* __restrict__ cc,
                   const int N,
                   int* __restrict__ assign_out,
                   const int* __restrict__ prev, const int pstride,
                   unsigned int* __restrict__ mismatch,
                   int* __restrict__ counts)
{
    __shared__ float xs[2][TM * DSL];   // 2 x 8 KB
    __shared__ float cs[2][TKC * DSL];  // 2 x 8 KB

    const int tid  = threadIdx.x;
    const int w    = tid >> 6;
    const int lane = tid & 63;
    const int tr   = tid >> 4;   // 0..15 (point dim: 4 rows each)
    const int tc   = tid & 15;   // 0..15 (centroid dim: 4 rows each)
    const long long rowbase = (long long)blockIdx.x * TM;

    float minv[4]; int mini[4];
#pragma unroll
    for (int i = 0; i < 4; ++i) { minv[i] = __builtin_inff(); mini[i] = 0; }

    const int r_st  = (w << 3) + (lane >> 3);
    const int slot4 = (lane & 7) << 2;

    // 4 global_load_lds per thread per STAGE (2 cs + 2 xs), rows 0..63 each
#define STAGE(BUF, S) do {                                                        \
        const int d0_    = ((S) & 7) * DSL;                                       \
        const int cbase_ = ((S) >> 3) * TKC;                                      \
        _Pragma("unroll")                                                         \
        for (int call = 0; call < 2; ++call) {                                    \
            int r  = (call << 5) + r_st;                                          \
            int dl = slot4 ^ (((r >> 2) & 7) << 2);                               \
            gld_lds16(cent + (long long)(cbase_ + r) * DD + d0_ + dl,             \
                      &cs[(BUF)][((call << 2) + w) << 8]);                        \
            long long p = rowbase + r; if (p > N - 1) p = N - 1;                  \
            gld_lds16(x + p * DD + d0_ + dl,                                      \
                      &xs[(BUF)][((call << 2) + w) << 8]);                        \
        }                                                                         \
    } while (0)

    STAGE(0, 0);
    int s = 0;
    float2v acc2[4][4];

#pragma unroll 1
    for (int chunk = 0; chunk < NCHUNK; ++chunk) {
        float cchalf[4];
#pragma unroll
        for (int j = 0; j < 4; ++j) {
            int r = (tc << 2) + j;
            cchalf[j] = 0.5f * cc[chunk * TKC + r];   // exact scale
        }
#pragma unroll
        for (int i = 0; i < 4; ++i)
#pragma unroll
            for (int j = 0; j < 4; ++j) acc2[i][j] = (float2v){0.0f, 0.0f};

#pragma unroll 1
        for (int sl = 0; sl < NSL; ++sl) {
            const int buf = s & 1;
            __syncthreads();                      // compiler drains vmcnt here
            if (s + 1 < NSLICES) STAGE(buf ^ 1, s + 1);
#pragma unroll
            for (int g = 0; g < 8; ++g) {
                const int dl = g << 2;
                float4v ax[4], bc[4];
#pragma unroll
                for (int i = 0; i < 4; ++i) {
                    int r = (tr << 2) + i;
                    ax[i] = *(const float4v*)&xs[buf][(r << 5) + (dl ^ (((r >> 2) & 7) << 2))];
                }
#pragma unroll
                for (int j = 0; j < 4; ++j) {
                    int r = (tc << 2) + j;
                    bc[j] = *(const float4v*)&cs[buf][(r << 5) + (dl ^ (((r >> 2) & 7) << 2))];
                }
#pragma unroll
                for (int i = 0; i < 4; ++i) {
                    const float2v axl = __builtin_shufflevector(ax[i], ax[i], 0, 1);
                    const float2v axh = __builtin_shufflevector(ax[i], ax[i], 2, 3);
#pragma unroll
                    for (int j = 0; j < 4; ++j) {
                        const float2v bcl = __builtin_shufflevector(bc[j], bc[j], 0, 1);
                        const float2v bch = __builtin_shufflevector(bc[j], bc[j], 2, 3);
                        float2v t = acc2[i][j];
                        t = __builtin_elementwise_fma(axl, bcl, t);   // v_pk_fma_f32
                        t = __builtin_elementwise_fma(axh, bch, t);   // v_pk_fma_f32
                        acc2[i][j] = t;
                    }
                }
            }
            ++s;
        }
        // fold this chunk into running min (registers only):
        // score = 0.5*cc - dot  (same argmin as the true distance — R10-verified)
        {
#pragma clang fp contract(off)
#pragma unroll
            for (int i = 0; i < 4; ++i)
#pragma unroll
                for (int j = 0; j < 4; ++j) {
                    int r = (tc << 2) + j;
                    float dot   = acc2[i][j][0] + acc2[i][j][1];
                    float score = cchalf[j] - dot;
                    if (score < minv[i]) { minv[i] = score; mini[i] = chunk * TKC + r; }
                }
        }
    }
#undef STAGE

    // reduce across the 16 tc lanes (bits 0..3 of lane), first-min tie-break
#pragma unroll
    for (int i = 0; i < 4; ++i) {
#pragma unroll
        for (int off = 1; off < 16; off <<= 1) {
            float ov = __shfl_xor(minv[i], off);
            int   oi = __shfl_xor(mini[i], off);
            if (ov < minv[i] || (ov == minv[i] && oi < mini[i])) { minv[i] = ov; mini[i] = oi; }
        }
    }
    if (tc == 0) {
        unsigned int mis = 0;
#pragma unroll
        for (int i = 0; i < 4; ++i) {
            long long p = rowbase + (tr << 2) + i;
            if (p < N) {
                assign_out[p] = mini[i];
                if (FIRST) {
                    atomicAdd(&counts[mini[i]], 1);      // fused hist
                }
                if (prev != nullptr && prev[p * pstride] != mini[i]) ++mis;
            }
        }
        if (mis) atomicAdd(mismatch, mis);
    }
}

// row-wise squared norms (one wave per row, 256 cols) — used for centroids only
__global__ void sqnorm_kernel(const float* __restrict__ m, float* __restrict__ out, const int n)
{
    const int w = threadIdx.x >> 6, lane = threadIdx.x & 63;
    const int row = (blockIdx.x << 2) + w;
    if (row >= n) return;
    const float4v v = *(const float4v*)&m[(long long)row * DD + (lane << 2)];
    float s = v[0]*v[0] + v[1]*v[1] + v[2]*v[2] + v[3]*v[3];
#pragma unroll
    for (int off = 1; off < 64; off <<= 1) s += __shfl_xor(s, off);
    if (lane == 0) out[row] = s;
}

// ---------------------------------------------------------------------------
// Segment-sum via counting sort + gather.
// Q40 fixed-point accumulation is order-independent => deterministic.
// (hist is fused into argmin pass 1's epilogue.)
// ---------------------------------------------------------------------------
__global__ __launch_bounds__(KK)
void scan_kernel(const int* __restrict__ counts, int* __restrict__ starts, int* __restrict__ cursor)
{
    __shared__ int buf[2][KK];
    const int t = threadIdx.x;
    const int v = counts[t];
    buf[0][t] = v;
    __syncthreads();
    int src = 0;
#pragma unroll
    for (int off = 1; off < KK; off <<= 1) {
        int val = buf[src][t];
        if (t >= off) val += buf[src][t - off];
        buf[src ^ 1][t] = val;
        src ^= 1;
        __syncthreads();
    }
    const int excl = buf[src][t] - v;
    starts[t] = excl;
    cursor[t] = excl;
}

__global__ void scatter_kernel(const int* __restrict__ assign, int* __restrict__ cursor,
                               int* __restrict__ idx, const int N)
{
    const int p = blockIdx.x * 256 + threadIdx.x;
    if (p >= N) return;
    const int a = assign[p];
    const int pos = atomicAdd(&cursor[a], 1);
    idx[pos] = p;
}

__global__ __launch_bounds__(256)
void gather_kernel(const float* __restrict__ x, const int* __restrict__ idx,
                   const int* __restrict__ starts, const int* __restrict__ counts,
                   unsigned long long* __restrict__ sums)
{
    const int c    = blockIdx.x / SPLIT;
    const int part = blockIdx.x % SPLIT;
    const int d    = threadIdx.x;
    const int start = starts[c], cnt = counts[c];
    const int chunk = (cnt + SPLIT - 1) / SPLIT;
    const int i0 = part * chunk;
    int i1 = i0 + chunk; if (i1 > cnt) i1 = cnt;
    if (i1 <= i0) return;

    long long acc = 0;
    int i = i0;
    for (; i + 4 <= i1; i += 4) {
        const int p0 = idx[start + i + 0];
        const int p1 = idx[start + i + 1];
        const int p2 = idx[start + i + 2];
        const int p3 = idx[start + i + 3];
        const float v0 = x[(long long)p0 * DD + d];
        const float v1 = x[(long long)p1 * DD + d];
        const float v2 = x[(long long)p2 * DD + d];
        const float v3 = x[(long long)p3 * DD + d];
        acc += __double2ll_rn((double)v0 * 1099511627776.0);   // 2^40
        acc += __double2ll_rn((double)v1 * 1099511627776.0);
        acc += __double2ll_rn((double)v2 * 1099511627776.0);
        acc += __double2ll_rn((double)v3 * 1099511627776.0);
    }
    for (; i < i1; ++i) {
        const int p = idx[start + i];
        acc += __double2ll_rn((double)x[(long long)p * DD + d] * 1099511627776.0);
    }
    atomicAdd(&sums[(size_t)c * DD + d], (unsigned long long)acc);
}

// EMA update + squared norms of updated centroids
__global__ void update_kernel(const float* __restrict__ cent,
                              const unsigned long long* __restrict__ sums,
                              const int* __restrict__ counts,
                              float* __restrict__ updated, float* __restrict__ cc2)
{
    const int c = blockIdx.x, d = threadIdx.x;
    const int w = d >> 6, lane = d & 63;
    __shared__ float red[4];
    float u;
    {
#pragma clang fp contract(off)
        const float cnt = (float)counts[c];
        const float sf  = (float)((double)(long long)sums[(size_t)c * DD + d] * (1.0 / 1099511627776.0));
        const float nc  = sf / cnt;
        u = 0.01f * cent[(size_t)c * DD + d] + 0.99f * nc;
    }
    updated[(size_t)c * DD + d] = u;
    float s = u * u;
#pragma unroll
    for (int off = 1; off < 64; off <<= 1) s += __shfl_xor(s, off);
    if (lane == 0) red[w] = s;
    __syncthreads();
    if (d == 0) cc2[c] = (red[0] + red[1]) + (red[2] + red[3]);
}

// final select per match flag; everything emitted as f32
__global__ void output_kernel(const unsigned int* __restrict__ mismatch,
                              const int* __restrict__ a1, const int* __restrict__ a2,
                              const float* __restrict__ cent, const float* __restrict__ updated,
                              float* __restrict__ out, const int N, const int total)
{
    const int g = blockIdx.x * 256 + threadIdx.x;
    if (g >= total) return;
    const bool match = (*mismatch == 0u);
    if (g < N)       out[g] = (float)(match ? a2[g] : a1[g]);
    else if (g == N) out[g] = match ? 1.0f : 0.0f;
    else {
        const int e = g - N - 1;
        out[g] = match ? updated[e] : cent[e];
    }
}

extern "C" void kernel_launch(void* const* d_in, const int* in_sizes, int n_in,
                              void* d_out, int out_size, void* d_ws, size_t ws_size,
                              hipStream_t stream)
{
    const float* x    = (const float*)d_in[0];
    const float* cent = (const float*)d_in[1];
    const int*   prev = (const int*)d_in[2];
    const int N = in_sizes[0] / DD;
    const int pstride = (n_in >= 3 && in_sizes[2] >= 2 * N) ? 2 : 1;  // int64 defensive

    char* ws = (char*)d_ws;
    size_t off = 0;
    auto alloc = [&](size_t b) { void* p = ws + off; off += (b + 255) & ~(size_t)255; return p; };
    int*   assign1 = (int*)alloc((size_t)N * 4);
    int*   assign2 = (int*)alloc((size_t)N * 4);
    float* cc      = (float*)alloc(KK * 4);
    float* cc2v    = (float*)alloc(KK * 4);
    int*   counts  = (int*)alloc(KK * 4);
    int*   starts  = (int*)alloc(KK * 4);
    int*   cursor  = (int*)alloc(KK * 4);
    int*   idx     = (int*)alloc((size_t)N * 4);
    unsigned long long* sums = (unsigned long long*)alloc((size_t)KK * DD * 8);
    float* updated = (float*)alloc((size_t)KK * DD * 4);
    unsigned int* mismatch = (unsigned int*)alloc(256);

    hipMemsetAsync(counts, 0, KK * 4, stream);
    hipMemsetAsync(sums, 0, (size_t)KK * DD * 8, stream);
    hipMemsetAsync(mismatch, 0, 4, stream);

    sqnorm_kernel<<<(KK + 3) / 4, 256, 0, stream>>>(cent, cc, KK);

    const int gb = (N + TM - 1) / TM;
    argmin_kernel<true><<<gb, 256, 0, stream>>>(x, cent, cc, N, assign1,
                                                prev, pstride, mismatch, counts);

    // counting-sort + gather segment sum (hist fused into argmin pass 1)
    scan_kernel<<<1, KK, 0, stream>>>(counts, starts, cursor);
    scatter_kernel<<<(N + 255) / 256, 256, 0, stream>>>(assign1, cursor, idx, N);
    gather_kernel<<<KK * SPLIT, 256, 0, stream>>>(x, idx, starts, counts, sums);

    update_kernel<<<KK, 256, 0, stream>>>(cent, sums, counts, updated, cc2v);

    argmin_kernel<false><<<gb, 256, 0, stream>>>(x, updated, cc2v, N, assign2,
                                                 nullptr, 1, nullptr, nullptr);

    output_kernel<<<(out_size + 255) / 256, 256, 0, stream>>>(mismatch, assign1, assign2,
                                                              cent, updated, (float*)d_out,
                                                              N, out_size);
}

// Round 14
// 1038.511 us; speedup vs baseline: 1.2466x; 1.0620x over previous
//
#include <hip/hip_runtime.h>
#include <math.h>

#define DD 256
#define KK 512
#define TM 64
#define TKC 128
#define NCHUNK 4
#define DSL 32
#define NSL 8
#define NSLICES 32
#define SPLIT 8

typedef float float4v __attribute__((ext_vector_type(4)));
typedef float float2v __attribute__((ext_vector_type(2)));

__device__ __forceinline__ void gld_lds16(const void* g, void* l) {
    __builtin_amdgcn_global_load_lds((const __attribute__((address_space(1))) void*)g,
                                     (__attribute__((address_space(3))) void*)l, 16, 0, 0);
}

// ---------------------------------------------------------------------------
// argmin over K=512 centroids for a 64-point block.
// Round-14: main loop byte-exact R10 (TM=64, TKC=128, 48KB LDS, 3 blk/CU,
// pk_fma core, score = 0.5*cc - dot).  R10-R13 established this as the
// structural floor: LDS pipe 375us + 83us conflicts ~ 450us measured;
// occupancy raises (R13) and tile growth (R11/R12) both fail.
// This round: tail fusions only (epilogue-class, proven-safe):
//  * pass 2 writes out[p] directly (match ? mini : a1[p]) — output_kernel gone
//  * counts/mismatch zeroed in sqnorm, sums zeroed in scatter — memsets gone
//  * update writes out[N] flag + centroid tail using final mismatch
// ---------------------------------------------------------------------------
template<bool FIRST>
__global__ __launch_bounds__(256, 2)
void argmin_kernel(const float* __restrict__ x, const float* __restrict__ cent,
                   const float* __restrict__ cc,
                   const int N,
                   int* __restrict__ assign_out,
                   const int* __restrict__ prev, const int pstride,
                   unsigned int* __restrict__ mismatch,
                   int* __restrict__ counts,
                   float* __restrict__ out, const int* __restrict__ a1)
{
    __shared__ float xs[2][TM * DSL];   // 2 x 8 KB
    __shared__ float cs[2][TKC * DSL];  // 2 x 16 KB

    const int tid  = threadIdx.x;
    const int w    = tid >> 6;
    const int lane = tid & 63;
    const int tr   = tid >> 4;   // 0..15 (point dim: 4 rows each)
    const int tc   = tid & 15;   // 0..15 (centroid dim)
    const long long rowbase = (long long)blockIdx.x * TM;

    // pass 2: match flag is final (argmin1 completed earlier in the stream)
    const bool match = FIRST ? false : (*mismatch == 0u);

    float minv[4]; int mini[4];
#pragma unroll
    for (int i = 0; i < 4; ++i) { minv[i] = __builtin_inff(); mini[i] = 0; }

    const int r_st  = (w << 3) + (lane >> 3);
    const int slot4 = (lane & 7) << 2;

    // 6 global_load_lds per thread per STAGE (4 cs calls + 2 xs calls)
#define STAGE(BUF, S) do {                                                        \
        const int d0_    = ((S) & 7) * DSL;                                       \
        const int cbase_ = ((S) >> 3) * TKC;                                      \
        _Pragma("unroll")                                                         \
        for (int call = 0; call < 4; ++call) {                                    \
            int r  = (call << 5) + r_st;                                          \
            int dl = slot4 ^ (((r >> 2) & 7) << 2);                               \
            gld_lds16(cent + (long long)(cbase_ + r) * DD + d0_ + dl,             \
                      &cs[(BUF)][((call << 2) + w) << 8]);                        \
            if (call < 2) {                                                       \
                long long p = rowbase + r; if (p > N - 1) p = N - 1;              \
                gld_lds16(x + p * DD + d0_ + dl,                                  \
                          &xs[(BUF)][((call << 2) + w) << 8]);                    \
            }                                                                     \
        }                                                                         \
    } while (0)

    STAGE(0, 0);
    int s = 0;
    float2v acc2[4][8];

#pragma unroll 1
    for (int chunk = 0; chunk < NCHUNK; ++chunk) {
        float cchalf[8];
#pragma unroll
        for (int j = 0; j < 8; ++j) {
            int r = ((j >> 2) << 6) + (tc << 2) + (j & 3);
            cchalf[j] = 0.5f * cc[chunk * TKC + r];   // exact scale
        }
#pragma unroll
        for (int i = 0; i < 4; ++i)
#pragma unroll
            for (int j = 0; j < 8; ++j) acc2[i][j] = (float2v){0.0f, 0.0f};

#pragma unroll 1
        for (int sl = 0; sl < NSL; ++sl) {
            const int buf = s & 1;
            __syncthreads();                      // compiler drains vmcnt here
            if (s + 1 < NSLICES) STAGE(buf ^ 1, s + 1);
#pragma unroll
            for (int g = 0; g < 8; ++g) {
                const int dl = g << 2;
                float4v ax[4], bc[8];
#pragma unroll
                for (int i = 0; i < 4; ++i) {
                    int r = (tr << 2) + i;
                    ax[i] = *(const float4v*)&xs[buf][(r << 5) + (dl ^ (((r >> 2) & 7) << 2))];
                }
#pragma unroll
                for (int j = 0; j < 8; ++j) {
                    int r = ((j >> 2) << 6) + (tc << 2) + (j & 3);
                    bc[j] = *(const float4v*)&cs[buf][(r << 5) + (dl ^ (((r >> 2) & 7) << 2))];
                }
#pragma unroll
                for (int i = 0; i < 4; ++i) {
                    const float2v axl = __builtin_shufflevector(ax[i], ax[i], 0, 1);
                    const float2v axh = __builtin_shufflevector(ax[i], ax[i], 2, 3);
#pragma unroll
                    for (int j = 0; j < 8; ++j) {
                        const float2v bcl = __builtin_shufflevector(bc[j], bc[j], 0, 1);
                        const float2v bch = __builtin_shufflevector(bc[j], bc[j], 2, 3);
                        float2v t = acc2[i][j];
                        t = __builtin_elementwise_fma(axl, bcl, t);   // v_pk_fma_f32
                        t = __builtin_elementwise_fma(axh, bch, t);   // v_pk_fma_f32
                        acc2[i][j] = t;
                    }
                }
            }
            ++s;
        }
        // fold this chunk into running min (registers only):
        // score = 0.5*cc - dot  (same argmin as the true distance — R10-verified)
        {
#pragma clang fp contract(off)
#pragma unroll
            for (int i = 0; i < 4; ++i)
#pragma unroll
                for (int j = 0; j < 8; ++j) {
                    int r = ((j >> 2) << 6) + (tc << 2) + (j & 3);
                    float dot   = acc2[i][j][0] + acc2[i][j][1];
                    float score = cchalf[j] - dot;
                    if (score < minv[i]) { minv[i] = score; mini[i] = chunk * TKC + r; }
                }
        }
    }
#undef STAGE

    // reduce across the 16 tc lanes (bits 0..3 of lane), first-min tie-break
#pragma unroll
    for (int i = 0; i < 4; ++i) {
#pragma unroll
        for (int off = 1; off < 16; off <<= 1) {
            float ov = __shfl_xor(minv[i], off);
            int   oi = __shfl_xor(mini[i], off);
            if (ov < minv[i] || (ov == minv[i] && oi < mini[i])) { minv[i] = ov; mini[i] = oi; }
        }
    }
    if (tc == 0) {
        unsigned int mis = 0;
#pragma unroll
        for (int i = 0; i < 4; ++i) {
            long long p = rowbase + (tr << 2) + i;
            if (p < N) {
                if (FIRST) {
                    assign_out[p] = mini[i];
                    atomicAdd(&counts[mini[i]], 1);      // fused hist
                    if (prev != nullptr && prev[p * pstride] != mini[i]) ++mis;
                } else {
                    // fused output: assignments section of out
                    out[p] = match ? (float)mini[i] : (float)a1[p];
                }
            }
        }
        if (FIRST && mis) atomicAdd(mismatch, mis);
    }
}

// row-wise squared norms (one wave per row) — centroids only.
// Block 0 also zeroes counts + mismatch (replaces two hipMemsetAsync).
__global__ void sqnorm_kernel(const float* __restrict__ m, float* __restrict__ out, const int n,
                              int* __restrict__ counts, unsigned int* __restrict__ mismatch)
{
    if (blockIdx.x == 0) {
        const int t = threadIdx.x;
        counts[t] = 0; counts[t + 256] = 0;
        if (t == 0) *mismatch = 0u;
    }
    const int w = threadIdx.x >> 6, lane = threadIdx.x & 63;
    const int row = (blockIdx.x << 2) + w;
    if (row >= n) return;
    const float4v v = *(const float4v*)&m[(long long)row * DD + (lane << 2)];
    float s = v[0]*v[0] + v[1]*v[1] + v[2]*v[2] + v[3]*v[3];
#pragma unroll
    for (int off = 1; off < 64; off <<= 1) s += __shfl_xor(s, off);
    if (lane == 0) out[row] = s;
}

// ---------------------------------------------------------------------------
// Segment-sum via counting sort + gather.
// Q40 fixed-point accumulation is order-independent => deterministic.
// ---------------------------------------------------------------------------
__global__ __launch_bounds__(KK)
void scan_kernel(const int* __restrict__ counts, int* __restrict__ starts, int* __restrict__ cursor)
{
    __shared__ int buf[2][KK];
    const int t = threadIdx.x;
    const int v = counts[t];
    buf[0][t] = v;
    __syncthreads();
    int src = 0;
#pragma unroll
    for (int off = 1; off < KK; off <<= 1) {
        int val = buf[src][t];
        if (t >= off) val += buf[src][t - off];
        buf[src ^ 1][t] = val;
        src ^= 1;
        __syncthreads();
    }
    const int excl = buf[src][t] - v;
    starts[t] = excl;
    cursor[t] = excl;
}

// scatter point ids into buckets; also zeroes sums (replaces hipMemsetAsync)
__global__ void scatter_kernel(const int* __restrict__ assign, int* __restrict__ cursor,
                               int* __restrict__ idx, const int N,
                               unsigned long long* __restrict__ sums)
{
    const int gid    = blockIdx.x * 256 + threadIdx.x;
    const int stride = gridDim.x * 256;
    for (int e = gid; e < KK * DD; e += stride) sums[e] = 0ull;   // consumed by gather (next dispatch)
    if (gid >= N) return;
    const int a = assign[gid];
    const int pos = atomicAdd(&cursor[a], 1);
    idx[pos] = gid;
}

__global__ __launch_bounds__(256)
void gather_kernel(const float* __restrict__ x, const int* __restrict__ idx,
                   const int* __restrict__ starts, const int* __restrict__ counts,
                   unsigned long long* __restrict__ sums)
{
    const int c    = blockIdx.x / SPLIT;
    const int part = blockIdx.x % SPLIT;
    const int d    = threadIdx.x;
    const int start = starts[c], cnt = counts[c];
    const int chunk = (cnt + SPLIT - 1) / SPLIT;
    const int i0 = part * chunk;
    int i1 = i0 + chunk; if (i1 > cnt) i1 = cnt;
    if (i1 <= i0) return;

    long long acc = 0;
    int i = i0;
    for (; i + 4 <= i1; i += 4) {
        const int p0 = idx[start + i + 0];
        const int p1 = idx[start + i + 1];
        const int p2 = idx[start + i + 2];
        const int p3 = idx[start + i + 3];
        const float v0 = x[(long long)p0 * DD + d];
        const float v1 = x[(long long)p1 * DD + d];
        const float v2 = x[(long long)p2 * DD + d];
        const float v3 = x[(long long)p3 * DD + d];
        acc += __double2ll_rn((double)v0 * 1099511627776.0);   // 2^40
        acc += __double2ll_rn((double)v1 * 1099511627776.0);
        acc += __double2ll_rn((double)v2 * 1099511627776.0);
        acc += __double2ll_rn((double)v3 * 1099511627776.0);
    }
    for (; i < i1; ++i) {
        const int p = idx[start + i];
        acc += __double2ll_rn((double)x[(long long)p * DD + d] * 1099511627776.0);
    }
    atomicAdd(&sums[(size_t)c * DD + d], (unsigned long long)acc);
}

// EMA update + squared norms of updated centroids.
// Also writes the output tail (flag + centroid section) using final mismatch.
__global__ void update_kernel(const float* __restrict__ cent,
                              const unsigned long long* __restrict__ sums,
                              const int* __restrict__ counts,
                              float* __restrict__ updated, float* __restrict__ cc2,
                              const unsigned int* __restrict__ mismatch,
                              float* __restrict__ out, const int N)
{
    const int c = blockIdx.x, d = threadIdx.x;
    const int w = d >> 6, lane = d & 63;
    __shared__ float red[4];
    const bool match = (*mismatch == 0u);
    const float cv = cent[(size_t)c * DD + d];
    float u;
    {
#pragma clang fp contract(off)
        const float cnt = (float)counts[c];
        const float sf  = (float)((double)(long long)sums[(size_t)c * DD + d] * (1.0 / 1099511627776.0));
        const float nc  = sf / cnt;
        u = 0.01f * cv + 0.99f * nc;
    }
    updated[(size_t)c * DD + d] = u;
    // fused output: centroid section + flag
    out[(size_t)N + 1 + (size_t)c * DD + d] = match ? u : cv;
    if (c == 0 && d == 0) out[N] = match ? 1.0f : 0.0f;
    float s = u * u;
#pragma unroll
    for (int off = 1; off < 64; off <<= 1) s += __shfl_xor(s, off);
    if (lane == 0) red[w] = s;
    __syncthreads();
    if (d == 0) cc2[c] = (red[0] + red[1]) + (red[2] + red[3]);
}

extern "C" void kernel_launch(void* const* d_in, const int* in_sizes, int n_in,
                              void* d_out, int out_size, void* d_ws, size_t ws_size,
                              hipStream_t stream)
{
    const float* x    = (const float*)d_in[0];
    const float* cent = (const float*)d_in[1];
    const int*   prev = (const int*)d_in[2];
    const int N = in_sizes[0] / DD;
    const int pstride = (n_in >= 3 && in_sizes[2] >= 2 * N) ? 2 : 1;  // int64 defensive

    char* ws = (char*)d_ws;
    size_t off = 0;
    auto alloc = [&](size_t b) { void* p = ws + off; off += (b + 255) & ~(size_t)255; return p; };
    int*   assign1 = (int*)alloc((size_t)N * 4);
    float* cc      = (float*)alloc(KK * 4);
    float* cc2v    = (float*)alloc(KK * 4);
    int*   counts  = (int*)alloc(KK * 4);
    int*   starts  = (int*)alloc(KK * 4);
    int*   cursor  = (int*)alloc(KK * 4);
    int*   idx     = (int*)alloc((size_t)N * 4);
    unsigned long long* sums = (unsigned long long*)alloc((size_t)KK * DD * 8);
    float* updated = (float*)alloc((size_t)KK * DD * 4);
    unsigned int* mismatch = (unsigned int*)alloc(256);

    float* out = (float*)d_out;

    // sqnorm(cent) + zero counts/mismatch (fused)
    sqnorm_kernel<<<(KK + 3) / 4, 256, 0, stream>>>(cent, cc, KK, counts, mismatch);

    const int gb = (N + TM - 1) / TM;
    argmin_kernel<true><<<gb, 256, 0, stream>>>(x, cent, cc, N, assign1,
                                                prev, pstride, mismatch, counts,
                                                nullptr, nullptr);

    // counting-sort + gather segment sum (hist fused into argmin pass 1)
    scan_kernel<<<1, KK, 0, stream>>>(counts, starts, cursor);
    scatter_kernel<<<(N + 255) / 256, 256, 0, stream>>>(assign1, cursor, idx, N, sums);
    gather_kernel<<<KK * SPLIT, 256, 0, stream>>>(x, idx, starts, counts, sums);

    // EMA update + out tail (flag + centroid section, fused)
    update_kernel<<<KK, 256, 0, stream>>>(cent, sums, counts, updated, cc2v,
                                          mismatch, out, N);

    // pass 2 writes the assignment section of out directly
    argmin_kernel<false><<<gb, 256, 0, stream>>>(x, updated, cc2v, N, nullptr,
                                                 nullptr, 1, mismatch, nullptr,
                                                 out, assign1);
}